// Round 6
// baseline (407.041 us; speedup 1.0000x reference)
//
#include <hip/hip_runtime.h>
#include <math.h>

#define NB    2048
#define NSEG  20
#define MAXIT 48

typedef short bf8_t __attribute__((ext_vector_type(8)));
typedef float f32x4 __attribute__((ext_vector_type(4)));

#define cA21 ((float)0.161)
#define cA31 ((float)-0.008480655492356989)
#define cA32 ((float)0.335480655492357)
#define cA41 ((float)2.8971530571054935)
#define cA42 ((float)-6.359448489975075)
#define cA43 ((float)4.3622954328695815)
#define cA51 ((float)5.325864828439257)
#define cA52 ((float)-11.748883564062828)
#define cA53 ((float)7.4955393428898365)
#define cA54 ((float)-0.09249506636175525)
#define cA61 ((float)5.86145544294642)
#define cA62 ((float)-12.92096931784711)
#define cA63 ((float)8.159367898576159)
#define cA64 ((float)-0.071584973281401)
#define cA65 ((float)-0.028269050394068383)
#define cB1  ((float)0.09646076681806523)
#define cB2  ((float)0.01)
#define cB3  ((float)0.4798896504144996)
#define cB4  ((float)1.379008574103742)
#define cB5  ((float)-3.290069515436081)
#define cB6  ((float)2.324710524099774)
#define cE1  ((float)-0.001780011052225777)
#define cE2  ((float)-0.0008164344596567469)
#define cE3  ((float)0.007880878010261995)
#define cE4  ((float)-0.1447110071732629)
#define cE5  ((float)0.5823571654525552)
#define cE6  ((float)-0.45808210592918697)
#define cE7  ((float)0.015151515151515152)

#define SUMB (cB1 + cB2 + cB3 + cB4 + cB5 + cB6)
#define SUME (cE1 + cE2 + cE3 + cE4 + cE5 + cE6 + cE7)

__device__ __forceinline__ void split2(float x, short &hi, short &lo) {
    unsigned u = __float_as_uint(x);
    hi = (short)(u >> 16);
    float r = x - __uint_as_float(u & 0xFFFF0000u);
    lo = (short)(__float_as_uint(r) >> 16);
}

__device__ __forceinline__ float softplus_f(float x) {
    float t = exp2f(-fabsf(x) * 1.442695040888963f);
    return fmaxf(x, 0.0f) + log2f(1.0f + t) * 0.6931471805599453f;
}

__device__ __forceinline__ unsigned pk(short a, short b) {
    return ((unsigned)(unsigned short)a) | (((unsigned)(unsigned short)b) << 16);
}

// W31[u][m] = sum_d W1[u][d]*W3[d][m]; b31[u] = sum_d W1[u][d]*b3[d]
__global__ void setup_kernel(const float* __restrict__ W1, const float* __restrict__ W3,
                             const float* __restrict__ b3,
                             float* __restrict__ W31, float* __restrict__ b31) {
    int idx = blockIdx.x * 256 + threadIdx.x;       // 64 blocks -> 16384
    int u = idx >> 7, m = idx & 127;
    float s = 0.f;
    for (int d = 0; d < 64; ++d)
        s = fmaf(W1[u * 64 + d], W3[d * 128 + m], s);
    W31[idx] = s;
    if (idx < 128) {
        float b = 0.f;
        for (int d = 0; d < 64; ++d)
            b = fmaf(W1[idx * 64 + d], b3[d], b);
        b31[idx] = b;
    }
}

// 512 threads = 8 waves; 8 elements in lockstep. State in u-space (128-dim)
// C-layout across ALL 8 waves: lane (wave,quad,col<8) holds u-rows jb..jb+3 of
// element col. Per eval: 2 GEMM phases (W2, W31). Per step: one dual W3 GEMM
// reconstructs y5 (waves 0-3) and err (waves 4-7) from running h2 sums.
__global__ __launch_bounds__(512)
void ode_kernel(const float* __restrict__ history,
                const float* __restrict__ W1, const float* __restrict__ b1,
                const float* __restrict__ W2, const float* __restrict__ b2,
                const float* __restrict__ W3, const float* __restrict__ b3,
                const float* __restrict__ W31w, const float* __restrict__ b31w,
                float* __restrict__ out)
{
    __shared__ alignas(16) short h1H[4 * 544], h1L[4 * 544];
    __shared__ alignas(16) short h2H[4 * 544], h2L[4 * 544];
    __shared__ alignas(16) short sH[4 * 544],  sL[4 * 544];
    __shared__ alignas(16) short eHB[4 * 544], eLB[4 * 544];
    __shared__ float errB[8 * 68];
    __shared__ float partS[32];

    const int tid  = threadIdx.x;
    const int wave = tid >> 6, lane = tid & 63;
    const int quad = lane >> 4, col = lane & 15;
    const int jb   = 16 * wave + 4 * quad;          // u-row base (0..127)
    const int jb3  = 16 * (wave & 3) + 4 * quad;    // d-row base (0..63)
    const bool cr  = (col < 8);
    const bool w03 = (wave < 4);

    const int wIdxC = (jb >> 5) * 544 + ((jb >> 3) & 3) * 136 + (jb & 7) + col * 8;

    // ---- persistent weight A-fragments (bf16 hi/lo) ----
    bf8_t A2h[4], A2l[4], A31h[4], A31l[4], A3h[4], A3l[4];
#pragma unroll
    for (int c = 0; c < 4; ++c) {
        const float* p = W2 + (size_t)(16 * wave + col) * 128 + 32 * c + 8 * quad;
        bf8_t h, l;
#pragma unroll
        for (int j = 0; j < 8; ++j) { short hs, ls; split2(p[j], hs, ls); h[j] = hs; l[j] = ls; }
        A2h[c] = h; A2l[c] = l;
    }
#pragma unroll
    for (int c = 0; c < 4; ++c) {
        const float* p = W31w + (size_t)(16 * wave + col) * 128 + 32 * c + 8 * quad;
        bf8_t h, l;
#pragma unroll
        for (int j = 0; j < 8; ++j) { short hs, ls; split2(p[j], hs, ls); h[j] = hs; l[j] = ls; }
        A31h[c] = h; A31l[c] = l;
    }
#pragma unroll
    for (int c = 0; c < 4; ++c) {
        const float* p = W3 + (size_t)(16 * (wave & 3) + col) * 128 + 32 * c + 8 * quad;
        bf8_t h, l;
#pragma unroll
        for (int j = 0; j < 8; ++j) { short hs, ls; split2(p[j], hs, ls); h[j] = hs; l[j] = ls; }
        A3h[c] = h; A3l[c] = l;
    }
    const f32x4 b1f  = *(const f32x4*)(b1 + jb);
    const f32x4 b2f  = *(const f32x4*)(b2 + jb);
    const f32x4 b31f = *(const f32x4*)(b31w + jb);
    const f32x4 b3v  = *(const f32x4*)(b3 + jb3);

    auto gemm3 = [&](const bf8_t* Ah, const bf8_t* Al,
                     const short* BH, const short* BL, int nch) -> f32x4 {
        bf8_t bh[4], bl[4];
#pragma unroll 4
        for (int c = 0; c < nch; ++c) {
            const int off = c * 544 + quad * 136 + col * 8;
            bh[c] = *(const bf8_t*)(BH + off);
            bl[c] = *(const bf8_t*)(BL + off);
        }
        f32x4 p1 = {0.f, 0.f, 0.f, 0.f}, p2 = {0.f, 0.f, 0.f, 0.f}, p3 = {0.f, 0.f, 0.f, 0.f};
#pragma unroll 4
        for (int c = 0; c < nch; ++c) {
            p1 = __builtin_amdgcn_mfma_f32_16x16x32_bf16(Al[c], bh[c], p1, 0, 0, 0);
            p2 = __builtin_amdgcn_mfma_f32_16x16x32_bf16(Ah[c], bl[c], p2, 0, 0, 0);
            p3 = __builtin_amdgcn_mfma_f32_16x16x32_bf16(Ah[c], bh[c], p3, 0, 0, 0);
        }
        f32x4 o;
#pragma unroll
        for (int r = 0; r < 4; ++r) o[r] = (p1[r] + p2[r]) + p3[r];
        return o;
    };

    // write h1 = softplus(uarg + b1) to h1 buffers
    auto wrH1 = [&](f32x4 ua) {
        if (cr) {
            short hh[4], ll[4];
#pragma unroll
            for (int r = 0; r < 4; ++r) {
                float v = softplus_f(ua[r] + b1f[r]);
                split2(v, hh[r], ll[r]);
            }
            *(uint2*)(h1H + wIdxC) = make_uint2(pk(hh[0], hh[1]), pk(hh[2], hh[3]));
            *(uint2*)(h1L + wIdxC) = make_uint2(pk(ll[0], ll[1]), pk(ll[2], ll[3]));
        }
    };
    auto wrSplit = [&](f32x4 v4, short* H, short* L) {
        if (cr) {
            short hh[4], ll[4];
#pragma unroll
            for (int r = 0; r < 4; ++r) split2(v4[r], hh[r], ll[r]);
            *(uint2*)(H + wIdxC) = make_uint2(pk(hh[0], hh[1]), pk(hh[2], hh[3]));
            *(uint2*)(L + wIdxC) = make_uint2(pk(ll[0], ll[1]), pk(ll[2], ll[3]));
        }
    };

    // ---- init: y0, yU = y0@W1.T, kU1 = f(y0) in u-space ----
    const int eb = blockIdx.x * 8;
    f32x4 y = {0.f, 0.f, 0.f, 0.f};
    if (w03 && cr)
        y = *(const f32x4*)(history + ((size_t)(eb + col) * 15 + 14) * 64 + jb);
    float dt = 0.1f, t = 0.f;
    f32x4 yU, yU5, kU1, kU2, kU3, kU4, kU5, kU6, kU7, h2keep, h2last, SA, SE, y5v;

    if (w03) wrSplit(y, h2H, h2L);    // stage y0 (chunks 0-1) into h2 buffers
    __syncthreads();
    {
        bf8_t A1h[2], A1l[2];
#pragma unroll
        for (int c = 0; c < 2; ++c) {
            const float* p = W1 + (size_t)(16 * wave + col) * 64 + 32 * c + 8 * quad;
            bf8_t h, l;
#pragma unroll
            for (int j = 0; j < 8; ++j) { short hs, ls; split2(p[j], hs, ls); h[j] = hs; l[j] = ls; }
            A1h[c] = h; A1l[c] = l;
        }
        yU = gemm3(A1h, A1l, h2H, h2L, 2);
    }
    wrH1(yU);                          // h1 of eval(y0)
    __syncthreads();
    {
        f32x4 p = gemm3(A2h, A2l, h1H, h1L, 4);
#pragma unroll
        for (int r = 0; r < 4; ++r) p[r] = softplus_f(p[r] + b2f[r]);
        h2keep = p;
        wrSplit(p, h2H, h2L);
    }
    __syncthreads();
    {
        f32x4 p = gemm3(A31h, A31l, h2H, h2L, 4);
#pragma unroll
        for (int r = 0; r < 4; ++r) kU1[r] = p[r] + b31f[r];
    }

#pragma unroll 1
    for (int seg = 1; seg <= NSEG; ++seg) {
        const float t1 = (float)seg;
        t = t1 - 1.0f;
        bool done = false;

#pragma unroll 1
        for (int it = 0; it < MAXIT; ++it) {
            const float h = fminf(dt, t1 - t);
#pragma unroll
            for (int r = 0; r < 4; ++r) { SA[r] = cB1 * h2keep[r]; SE[r] = cE1 * h2keep[r]; }

            // stage-2 argument
            {
                f32x4 ua;
#pragma unroll
                for (int r = 0; r < 4; ++r) ua[r] = fmaf(h, cA21 * kU1[r], yU[r]);
                wrH1(ua);
            }

#pragma unroll 1
            for (int st = 2; st <= 7; ++st) {
                __syncthreads();
                // phase A: W2 GEMM + softplus + SA/SE accumulate
                {
                    f32x4 p = gemm3(A2h, A2l, h1H, h1L, 4);
#pragma unroll
                    for (int r = 0; r < 4; ++r) p[r] = softplus_f(p[r] + b2f[r]);
                    float cb, ce;
                    switch (st) {
                        case 2: cb = cB2; ce = cE2; break;
                        case 3: cb = cB3; ce = cE3; break;
                        case 4: cb = cB4; ce = cE4; break;
                        case 5: cb = cB5; ce = cE5; break;
                        case 6: cb = cB6; ce = cE6; break;
                        default: cb = 0.f; ce = cE7; break;
                    }
#pragma unroll
                    for (int r = 0; r < 4; ++r) {
                        SA[r] = fmaf(cb, p[r], SA[r]);
                        SE[r] = fmaf(ce, p[r], SE[r]);
                    }
                    h2last = p;
                    wrSplit(p, h2H, h2L);
                }
                __syncthreads();
                // phase B: W31 GEMM -> kU_st; prepare next stage arg / or SA,SE write
                {
                    f32x4 p = gemm3(A31h, A31l, h2H, h2L, 4);
                    f32x4 kv;
#pragma unroll
                    for (int r = 0; r < 4; ++r) kv[r] = p[r] + b31f[r];
                    switch (st) {
                        case 2: kU2 = kv; break;
                        case 3: kU3 = kv; break;
                        case 4: kU4 = kv; break;
                        case 5: kU5 = kv; break;
                        case 6: kU6 = kv; break;
                        default: kU7 = kv; break;
                    }
                    if (st < 7) {
                        f32x4 ua;
#pragma unroll
                        for (int r = 0; r < 4; ++r) {
                            float sum;
                            switch (st + 1) {
                                case 3: sum = fmaf(cA31, kU1[r], cA32 * kU2[r]); break;
                                case 4: sum = fmaf(cA41, kU1[r], fmaf(cA42, kU2[r], cA43 * kU3[r])); break;
                                case 5: sum = fmaf(cA51, kU1[r], fmaf(cA52, kU2[r], fmaf(cA53, kU3[r], cA54 * kU4[r]))); break;
                                case 6: sum = fmaf(cA61, kU1[r], fmaf(cA62, kU2[r], fmaf(cA63, kU3[r], fmaf(cA64, kU4[r], cA65 * kU5[r])))); break;
                                default: sum = fmaf(cB1, kU1[r], fmaf(cB2, kU2[r], fmaf(cB3, kU3[r], fmaf(cB4, kU4[r], fmaf(cB5, kU5[r], cB6 * kU6[r]))))); break;
                            }
                            ua[r] = fmaf(h, sum, yU[r]);
                        }
                        if (st == 6) yU5 = ua;
                        wrH1(ua);
                    } else {
                        wrSplit(SA, sH, sL);
                        wrSplit(SE, eHB, eLB);
                    }
                }
            }

            __syncthreads();
            // dual W3 GEMM: waves 0-3 -> y5; waves 4-7 -> err, written to errB
            {
                const short* BH = w03 ? sH : eHB;
                const short* BL = w03 ? sL : eLB;
                f32x4 g = gemm3(A3h, A3l, BH, BL, 4);
                if (w03) {
                    if (cr) {
#pragma unroll
                        for (int r = 0; r < 4; ++r)
                            y5v[r] = fmaf(h, g[r] + (float)SUMB * b3v[r], y[r]);
                    }
                } else if (cr) {
                    f32x4 ev;
#pragma unroll
                    for (int r = 0; r < 4; ++r)
                        ev[r] = h * (g[r] + (float)SUME * b3v[r]);
                    *(f32x4*)(errB + col * 68 + jb3) = ev;
                }
            }
            __syncthreads();

            float rr = 0.f;
            if (w03 && cr) {
                f32x4 ev = *(const f32x4*)(errB + col * 68 + jb3);
#pragma unroll
                for (int r = 0; r < 4; ++r) {
                    float sc = fmaf(1e-3f, fmaxf(fabsf(y[r]), fabsf(y5v[r])), 1e-6f);
                    float q = ev[r] / sc;
                    rr = fmaf(q, q, rr);
                }
            }
            rr += __shfl_xor(rr, 16, 64);
            rr += __shfl_xor(rr, 32, 64);
            if (w03 && cr && quad == 0) partS[wave * 8 + (col & 7)] = rr;
            __syncthreads();

            const int cc = col & 7;
            float en = sqrtf((partS[cc] + partS[8 + cc] + partS[16 + cc] + partS[24 + cc])
                             * (1.0f / 64.0f));
            bool accept = (en <= 1.0f) && !done;
            float fac = 0.9f * exp2f(-0.2f * log2f(fmaxf(en, 1e-10f)));
            fac = fminf(fmaxf(fac, 0.2f), 10.0f);

            if (accept) {
                t += h;
                yU = yU5; kU1 = kU7; h2keep = h2last;
                if (w03 && cr) y = y5v;
            }
            if (!done) dt = h * fac;
            done = done || (t >= t1 - 1e-8f);

            if (__syncthreads_and(done ? 1 : 0)) break;
        }

        if (w03 && cr)
            *(f32x4*)(out + ((size_t)(eb + col) * NSEG + (seg - 1)) * 64 + jb) = y;
    }
}

extern "C" void kernel_launch(void* const* d_in, const int* in_sizes, int n_in,
                              void* d_out, int out_size, void* d_ws, size_t ws_size,
                              hipStream_t stream) {
    const float* history = (const float*)d_in[0];
    const float* W1 = (const float*)d_in[1];
    const float* b1 = (const float*)d_in[2];
    const float* W2 = (const float*)d_in[3];
    const float* b2 = (const float*)d_in[4];
    const float* W3 = (const float*)d_in[5];
    const float* b3 = (const float*)d_in[6];
    float* out = (float*)d_out;

    float* W31 = (float*)d_ws;            // 128*128 floats
    float* b31 = W31 + 128 * 128;         // 128 floats

    setup_kernel<<<dim3(64), dim3(256), 0, stream>>>(W1, W3, b3, W31, b31);
    ode_kernel<<<dim3(NB / 8), dim3(512), 0, stream>>>(history, W1, b1, W2, b2, W3, b3,
                                                       W31, b31, out);
}